// Round 9
// baseline (961.148 us; speedup 1.0000x reference)
//
#include <hip/hip_runtime.h>
#include <stdint.h>

// ---------------------------------------------------------------------------
// DecoderRNN: 100-step LSTM + additive attention + 3-layer MLP, B=1.
// R9 = R7 (622us steady baseline) + ONE change: no float atomics.
//   ctx partials + per-WG exp-sum go to per-WG slots ws_pv[32][100][260]
//   (plain sc1 stores; no RMW serialization in the pre-flag drain; no
//   zero-init; no prep race surface). Consumers read 32 slots + 32 sums as
//   pipelined independent IC loads and reduce in registers.
// Everything else (phase order, flag barrier, bf16 att_W regs, clh by w0)
// is exactly R7.
// ---------------------------------------------------------------------------

static constexpr float    L2E = 1.44269504088896341f;   // log2(e)
static constexpr float    K2  = 2.88539008177792681f;   // 2*log2(e)
static constexpr unsigned SPIN_LIMIT = 200000u;  // safety: never wedge the GPU

// workspace layout (float offsets)
static constexpr size_t OFF_BC   = 0;            // [2048][256] (VOut+att_b)*K2
static constexpr size_t OFF_YG   = 524288;       // [100][1024] y@W_ih.T + b_ih + b_hh
static constexpr size_t OFF_GRAW = 626688;       // [100][1024] full gate preacts
static constexpr size_t OFF_PV   = 729088;       // [32][100][260] pv partials + sum@256
static constexpr size_t PV_WG    = 26000;        // per-WG stride (100*260)
static constexpr size_t OFF_CLH  = 1561088;      // [100][256] cLSTM history
static constexpr size_t OFF_V1   = 1586688;      // [100][256]
static constexpr size_t OFF_V2   = 1612288;      // [100][256]
static constexpr size_t OFF_SYNC = 1637888;      // u32[512]: flags[64] | fv1@64[100] | fv2@192[100]

__device__ __forceinline__ float exp2fast(float x){ return __builtin_amdgcn_exp2f(x); }
__device__ __forceinline__ float rcpfast(float x){ return __builtin_amdgcn_rcpf(x); }
__device__ __forceinline__ float sigf(float x){ return rcpfast(1.f + exp2fast(-x*L2E)); }
__device__ __forceinline__ float tanhfast(float x){
  float E = exp2fast(x*K2);            // e^{2x}; inf/0 saturate correctly
  return 1.f - 2.f*rcpfast(E + 1.f);
}
__device__ __forceinline__ unsigned short f2bf(float f){
  unsigned b = __float_as_uint(f);
  return (unsigned short)((b + 0x7FFFu + ((b>>16)&1u))>>16);
}
__device__ __forceinline__ float bf2f(unsigned short u){ return __uint_as_float(((unsigned)u)<<16); }

// sc1 (agent-scope relaxed) accesses: coherent at Infinity Cache, bypass XCD L2s
__device__ __forceinline__ void gstore(float* p, float v){
  __hip_atomic_store(p, v, __ATOMIC_RELAXED, __HIP_MEMORY_SCOPE_AGENT);
}
__device__ __forceinline__ float gload(const float* p){
  return __hip_atomic_load(p, __ATOMIC_RELAXED, __HIP_MEMORY_SCOPE_AGENT);
}
__device__ __forceinline__ void gstore_u32(unsigned* p, unsigned v){
  __hip_atomic_store(p, v, __ATOMIC_RELAXED, __HIP_MEMORY_SCOPE_AGENT);
}
__device__ __forceinline__ unsigned gload_u32(const unsigned* p){
  return __hip_atomic_load(p, __ATOMIC_RELAXED, __HIP_MEMORY_SCOPE_AGENT);
}

// flag-array barrier: each WG writes its slot; wave0 polls all 32 slots.
__device__ __forceinline__ void fbar(unsigned* flags, int w, unsigned ep){
  asm volatile("s_waitcnt vmcnt(0)" ::: "memory");   // own sc1 stores at IC
  __syncthreads();
  if (threadIdx.x == 0) gstore_u32(&flags[w], ep);
  if (threadIdx.x < 64) {
    int lane = threadIdx.x;
    unsigned it = 0;
    for (;;) {
      unsigned v = (lane < 32) ? gload_u32(&flags[lane]) : ep;
      if (__all((int)(v >= ep))) break;
      if (++it > SPIN_LIMIT) break;                  // safety
    }
  }
  __syncthreads();
}
__device__ __forceinline__ void fwait_sleep(unsigned* flags, unsigned ep){
  if (threadIdx.x < 64) {
    int lane = threadIdx.x;
    unsigned it = 0;
    for (;;) {
      unsigned v = (lane < 32) ? gload_u32(&flags[lane]) : ep;
      if (__all((int)(v >= ep))) break;
      __builtin_amdgcn_s_sleep(2);
      if (++it > SPIN_LIMIT) break;
    }
  }
  __syncthreads();
}
__device__ __forceinline__ void arrive_cnt(unsigned* cnt){
  asm volatile("s_waitcnt vmcnt(0)" ::: "memory");
  __syncthreads();
  if (threadIdx.x == 0)
    __hip_atomic_fetch_add(cnt, 1u, __ATOMIC_RELAXED, __HIP_MEMORY_SCOPE_AGENT);
}
__device__ __forceinline__ void poll_ge(unsigned* p, unsigned tgt){
  if (threadIdx.x == 0){
    unsigned it = 0;
    while (gload_u32(p) < tgt){
      __builtin_amdgcn_s_sleep(2);
      if (++it > SPIN_LIMIT) break;
    }
  }
  __syncthreads();
}

// pipelined 32-slot pv read + 32 sum read -> (numerator, denominator)
__device__ __forceinline__ float pv_combine(const float* ws_pv, int t, int h){
  const float* pvb = ws_pv + (size_t)t*260 + h;
  const float* smb = ws_pv + (size_t)t*260 + 256;
  float pvv[32];
  #pragma unroll
  for (int i=0;i<32;i++) pvv[i] = gload(pvb + (size_t)i*PV_WG);
  float s0=0.f,s1=0.f,s2=0.f,s3=0.f;
  #pragma unroll
  for (int i=0;i<8;i++){
    s0 += gload(smb + (size_t)(4*i+0)*PV_WG);
    s1 += gload(smb + (size_t)(4*i+1)*PV_WG);
    s2 += gload(smb + (size_t)(4*i+2)*PV_WG);
    s3 += gload(smb + (size_t)(4*i+3)*PV_WG);
  }
  float st = (s0+s1)+(s2+s3);
  float a0=0.f,a1=0.f,a2=0.f,a3=0.f;
  #pragma unroll
  for (int i=0;i<8;i++){
    a0 += pvv[4*i+0]; a1 += pvv[4*i+1]; a2 += pvv[4*i+2]; a3 += pvv[4*i+3];
  }
  return ((a0+a1)+(a2+a3)) * rcpfast(st);
}

// ---------------------------------------------------------------------------
// prep kernel: Bc, yG, graw(0), sc1-zero sync flags
// ---------------------------------------------------------------------------
__global__ __launch_bounds__(256) void rnn_prep(
    const float* __restrict__ Y, const float* __restrict__ h0,
    const float* __restrict__ outE, const float* __restrict__ W_ih,
    const float* __restrict__ W_hh, const float* __restrict__ b_ih,
    const float* __restrict__ b_hh, const float* __restrict__ att_V,
    const float* __restrict__ att_b, float* __restrict__ ws)
{
  __shared__ float avT[32*257];
  __shared__ float oeL[8*257];
  __shared__ float yL[40];
  __shared__ float h0L[256];
  const int b = blockIdx.x, tid = threadIdx.x;
  float* ws_bc   = ws + OFF_BC;
  float* ws_yg   = ws + OFF_YG;
  float* ws_graw = ws + OFF_GRAW;

  if (b < 256) {                 // Bc[e][h] for 8 e-rows
    int e0 = b*8;
    for (int r=0;r<8;r++) oeL[r*257 + tid] = outE[(size_t)(e0+r)*256 + tid];
    int hl = tid & 31, er = tid >> 5;
    for (int ht=0; ht<8; ++ht) {
      __syncthreads();
      for (int i=0;i<32;i++){ int lin = tid + i*256; int r = lin>>8, j = lin&255;
        avT[r*257 + j] = att_V[(size_t)(ht*32+r)*256 + j]; }
      __syncthreads();
      float acc = 0.f;
      for (int j=0;j<256;j++) acc = fmaf(avT[hl*257 + j], oeL[er*257 + j], acc);
      int h = ht*32 + hl;
      ws_bc[(size_t)(e0+er)*256 + h] = (acc + att_b[h]) * K2;
    }
  } else if (b < 260) {          // yG for 25 timesteps
    int g = b - 256;
    for (int u=0; u<25; ++u) {
      int t = g*25 + u;
      __syncthreads();
      if (tid < 36) yL[tid] = Y[t*36 + tid];
      __syncthreads();
      for (int q=0;q<4;q++){
        int i = tid + 256*q;
        float acc = b_ih[i] + b_hh[i];
        for (int j=0;j<36;j++) acc = fmaf(W_ih[(size_t)i*36 + j], yL[j], acc);
        ws_yg[(size_t)t*1024 + i] = acc;
      }
    }
  } else if (b < 292) {          // graw(0) = yG(0) + W_hh@h0, 32 rows per block
    int s = b - 260;
    if (tid < 256) h0L[tid] = h0[tid];
    if (tid < 36)  yL[tid]  = Y[tid];
    __syncthreads();
    int r = tid>>3, l8 = tid&7;
    int R = s*32 + r;
    float acc = 0.f;
    for (int q=0;q<32;q++){ int j = l8*32 + q; acc = fmaf(W_hh[(size_t)R*256 + j], h0L[j], acc); }
    acc += __shfl_xor(acc,1); acc += __shfl_xor(acc,2); acc += __shfl_xor(acc,4);
    if (l8 == 0){
      float full = acc + b_ih[R] + b_hh[R];
      for (int j=0;j<36;j++) full = fmaf(W_ih[(size_t)R*36 + j], yL[j], full);
      ws_graw[R] = full;
    }
  } else {                       // b == 292: sc1-zero sync region (512 u32)
    unsigned* s0 = (unsigned*)(ws + OFF_SYNC);
    gstore_u32(&s0[tid], 0u); gstore_u32(&s0[tid + 256], 0u);
  }
}

// ---------------------------------------------------------------------------
// persistent main kernel
// roles: w<32 main, 32..35 MLP1, 36..37 MLP2, 38 MLP3
// ---------------------------------------------------------------------------
__global__ __launch_bounds__(512, 1) void rnn_main(
    const float* __restrict__ c0, const float* __restrict__ outE,
    const float* __restrict__ W_hh, const float* __restrict__ att_W,
    const float* __restrict__ att_vec,
    const float* __restrict__ W1, const float* __restrict__ b1,
    const float* __restrict__ W2, const float* __restrict__ b2,
    const float* __restrict__ W3, const float* __restrict__ b3,
    float* __restrict__ out, float* __restrict__ ws)
{
  __shared__ __align__(16) unsigned char smem[140288];
  const int w = blockIdx.x;
  const int tid = threadIdx.x;

  float* ws_yg    = ws + OFF_YG;
  float* ws_graw  = ws + OFF_GRAW;
  float* ws_pv    = ws + OFF_PV;      // [32][100][260]
  float* ws_clh   = ws + OFF_CLH;
  float* ws_v1    = ws + OFF_V1;
  float* ws_v2    = ws + OFF_V2;
  unsigned* flags = (unsigned*)(ws + OFF_SYNC);        // [32] (64 slots reserved)
  unsigned* fv1   = flags + 64;                        // [100]
  unsigned* fv2   = flags + 192;                       // [100]

  if (w < 32) {
    // ---------------- main role ----------------
    float*          bcS    = (float*)(smem);                 // [64][264] padded, *K2
    unsigned short* oeS    = (unsigned short*)(smem + 67584);// [64][256] bf16
    float*          whhS   = (float*)(smem + 100352);        // [32][260]
    float*          wsS    = (float*)(smem + 133632);        // [264] padded WS*K2
    float*          hS     = (float*)(smem + 134688);        // [256]
    float*          scoreS = (float*)(smem + 135712);        // [64]
    float*          wexpS  = (float*)(smem + 135968);        // [64]
    float*          pS     = (float*)(smem + 136224);        // [512]
    float*          avS    = (float*)(smem + 138272);        // [264] padded -2*att_vec

    // att_W rows in registers, bf16-packed: thread pair (r=tid>>1) holds 128
    // cols each as 64 u32 (2 bf16/reg).
    unsigned awP[64];
    { int r = tid>>1, p = tid&1;
      const float* arow = att_W + (size_t)r*256 + p*128;
      #pragma unroll
      for (int q=0;q<64;q++){
        unsigned lo = f2bf(arow[2*q]);
        unsigned hi = f2bf(arow[2*q+1]);
        awP[q] = lo | (hi<<16);
      } }
    float Vpart = 0.f;
    { int l8 = tid & 7;
      #pragma unroll
      for (int k=0;k<32;k++) Vpart += att_vec[l8*32 + k]; }

    const float* ws_bc = ws + OFF_BC;
    for (int i=0;i<32;i++){ int lin = tid + i*512; int col = lin>>8, h = lin&255;
      bcS[col*264 + h + (h>>5)] = ws_bc[(size_t)(w*64+col)*256 + h]; }
    for (int i=0;i<32;i++){ int lin = tid + i*512; int col = lin>>8, h = lin&255;
      oeS[col*256 + h] = f2bf(outE[(size_t)(w*64+col)*256 + h]); }
    for (int i=0;i<16;i++){ int lin = tid + i*512; int r = lin>>8, j = lin&255;
      whhS[r*260 + j] = W_hh[(size_t)(w*32+r)*256 + j]; }
    if (tid < 256) avS[tid + (tid>>5)] = -2.f * att_vec[tid];
    __syncthreads();

    for (int t = 0; t < 100; ++t) {
      // ---- phase 1: cross-WG reads (sc1, pipelined) ----
      float ig, fg, gg, og, c;
      if (tid < 256) {
        const float* g = ws_graw + (size_t)t*1024;
        ig = gload(&g[tid]);     fg = gload(&g[256+tid]);
        gg = gload(&g[512+tid]); og = gload(&g[768+tid]);
        if (t == 0) c = c0[tid];
        else        c = pv_combine(ws_pv, t-1, tid);
      }
      // ---- phase 2: LSTM elementwise ----
      if (tid < 256) {
        float cl = sigf(fg)*c + sigf(ig)*tanhfast(gg);
        float hn = sigf(og)*tanhfast(cl);
        hS[tid] = hn;
        if (w == 0) gstore(&ws_clh[(size_t)t*256 + tid], cl);
      }
      __syncthreads();
      // ---- phase 3: WS = att_W @ h from bf16-packed registers ----
      { int r = tid>>1, p = tid&1;
        const float4* h4 = (const float4*)(hS + p*128);
        float acc = 0.f;
        #pragma unroll
        for (int i=0;i<32;i++){
          float4 hv = h4[i];
          unsigned pk0 = awP[2*i], pk1 = awP[2*i+1];
          acc = fmaf(__uint_as_float(pk0<<16),           hv.x, acc);
          acc = fmaf(__uint_as_float(pk0 & 0xffff0000u), hv.y, acc);
          acc = fmaf(__uint_as_float(pk1<<16),           hv.z, acc);
          acc = fmaf(__uint_as_float(pk1 & 0xffff0000u), hv.w, acc);
        }
        acc += __shfl_xor(acc, 1);
        if (p == 0) wsS[r + (r>>5)] = acc * K2; }
      __syncthreads();
      // ---- phase 4: scores for 64 e-cols (8 threads/col x 32 h) ----
      { int col = tid >> 3, l8 = tid & 7;
        const float* bcR = bcS + col*264 + l8*33;
        const float* wsR = wsS + l8*33;
        const float* avR = avS + l8*33;
        float acc = Vpart;
        #pragma unroll
        for (int k=0;k<32;k++){
          float E = exp2fast(bcR[k] + wsR[k]);         // e^{2x}
          acc = fmaf(avR[k], rcpfast(E + 1.f), acc);   // v*(1-2r)
        }
        acc += __shfl_xor(acc,1); acc += __shfl_xor(acc,2); acc += __shfl_xor(acc,4);
        if (l8 == 0) scoreS[col] = acc; }
      __syncthreads();
      // ---- phase 5: exp (no max; |score|<~25) + per-WG sum -> slot ----
      if (tid < 64) {
        float ev = exp2fast(scoreS[tid] * L2E);
        wexpS[tid] = ev;
        float s = ev;
        #pragma unroll
        for (int d=1; d<64; d<<=1) s += __shfl_xor(s, d);
        if (tid == 0) gstore(&ws_pv[(size_t)w*PV_WG + (size_t)t*260 + 256], s);
      }
      __syncthreads();
      // ---- phase 6: partial ctx over this WG's 64 e-cols -> own slot ----
      { int h = tid & 255, half = tid >> 8;
        float accp = 0.f;
        #pragma unroll
        for (int i=0;i<32;i++){ int lc = half*32 + i;
          accp = fmaf(wexpS[lc], bf2f(oeS[lc*256 + h]), accp); }
        pS[half*256 + h] = accp; }
      __syncthreads();
      if (tid < 256)
        gstore(&ws_pv[(size_t)w*PV_WG + (size_t)t*260 + tid], pS[tid] + pS[256 + tid]);
      // ---- phase 7: gates_raw(t+1) slice: rows w*32..w*32+31 ----
      if (t <= 98) {
        int r32 = tid >> 4, l16 = tid & 15;
        float acc2 = 0.f;
        #pragma unroll
        for (int q=0;q<16;q++){ int j = l16 + 16*q; acc2 = fmaf(whhS[r32*260 + j], hS[j], acc2); }
        acc2 += __shfl_xor(acc2,1); acc2 += __shfl_xor(acc2,2);
        acc2 += __shfl_xor(acc2,4); acc2 += __shfl_xor(acc2,8);
        if (l16 == 0){ int R = w*32 + r32;
          gstore(&ws_graw[(size_t)(t+1)*1024 + R], acc2 + ws_yg[(size_t)(t+1)*1024 + R]); }
      }
      fbar(flags, w, (unsigned)(t+1));
    }
    // epilogue: c_final = ctx(99)
    if (w == 0 && tid < 256)
      out[3600 + tid] = pv_combine(ws_pv, 99, tid);
  } else if (w < 36) {
    // ---------------- MLP1: 64 rows of W1[256][512] ----------------
    float* wmS = (float*)(smem);
    float* vbS = (float*)(smem + 133632);
    int m = w - 32;
    for (int i=0;i<64;i++){ int lin = tid + i*512; int r = lin>>9, k = lin&511;
      wmS[r*520 + k + (k>>6)] = W1[(size_t)(m*64+r)*512 + k]; }
    __syncthreads();
    for (int s=0; s<100; ++s){
      fwait_sleep(flags, (unsigned)(s+1));
      { float val;
        if (tid < 256) val = gload(&ws_clh[(size_t)s*256 + tid]);
        else           val = pv_combine(ws_pv, s, tid - 256);
        vbS[tid + (tid>>6)] = val; }
      __syncthreads();
      int row = tid >> 3, l8 = tid & 7;
      const float* wr = wmS + row*520 + l8*65;
      const float* vr = vbS + l8*65;
      float acc = 0.f;
      #pragma unroll
      for (int q=0;q<64;q++) acc = fmaf(wr[q], vr[q], acc);
      acc += __shfl_xor(acc,1); acc += __shfl_xor(acc,2); acc += __shfl_xor(acc,4);
      if (l8 == 0){ int i = m*64 + row; gstore(&ws_v1[(size_t)s*256 + i], fmaxf(acc + b1[i], 0.f)); }
      arrive_cnt(&fv1[s]);
      __syncthreads();
    }
  } else if (w < 38) {
    // ---------------- MLP2: 128 rows of W2[256][256] ----------------
    float* wmS = (float*)(smem);
    float* vbS = (float*)(smem + 133632);
    int m = w - 36;
    for (int i=0;i<64;i++){ int lin = tid + i*512; int r = lin>>8, k = lin&255;
      wmS[r*260 + k + (k>>6)] = W2[(size_t)(m*128+r)*256 + k]; }
    __syncthreads();
    for (int s=0; s<100; ++s){
      poll_ge(&fv1[s], 4u);
      if (tid < 256) vbS[tid + (tid>>6)] = gload(&ws_v1[(size_t)s*256 + tid]);
      __syncthreads();
      int row = tid >> 2, l4 = tid & 3;
      const float* wr = wmS + row*260 + l4*65;
      const float* vr = vbS + l4*65;
      float acc = 0.f;
      #pragma unroll
      for (int q=0;q<64;q++) acc = fmaf(wr[q], vr[q], acc);
      acc += __shfl_xor(acc,1); acc += __shfl_xor(acc,2);
      if (l4 == 0){ int i = m*128 + row; gstore(&ws_v2[(size_t)s*256 + i], fmaxf(acc + b2[i], 0.f)); }
      arrive_cnt(&fv2[s]);
      __syncthreads();
    }
  } else {
    // ---------------- MLP3: W3[36][256] -> out ----------------
    float* wmS = (float*)(smem);
    float* vbS = (float*)(smem + 37440);
    for (int lin = tid; lin < 36*256; lin += 512){ int r = lin>>8, k = lin&255;
      wmS[r*260 + k + (k>>6)] = W3[(size_t)r*256 + k]; }
    __syncthreads();
    for (int s=0; s<100; ++s){
      poll_ge(&fv2[s], 2u);
      if (tid < 256) vbS[tid + (tid>>6)] = gload(&ws_v2[(size_t)s*256 + tid]);
      __syncthreads();
      if (tid < 288) {
        int row = tid >> 3, l8 = tid & 7;
        int kb = l8*32;
        const float* wr = wmS + row*260 + kb + (kb>>6);
        const float* vr = vbS + kb + (kb>>6);
        float acc = 0.f;
        #pragma unroll
        for (int q=0;q<32;q++) acc = fmaf(wr[q], vr[q], acc);
        acc += __shfl_xor(acc,1); acc += __shfl_xor(acc,2); acc += __shfl_xor(acc,4);
        if (l8 == 0) out[s*36 + row] = acc + b3[row];   // visible at kernel end
      }
      __syncthreads();
    }
  }
}

// ---------------------------------------------------------------------------
extern "C" void kernel_launch(void* const* d_in, const int* in_sizes, int n_in,
                              void* d_out, int out_size, void* d_ws, size_t ws_size,
                              hipStream_t stream) {
  (void)in_sizes; (void)n_in; (void)out_size; (void)ws_size;
  const float* Y       = (const float*)d_in[0];
  const float* h0      = (const float*)d_in[1];
  const float* c0      = (const float*)d_in[2];
  const float* outEnc  = (const float*)d_in[3];
  const float* W_ih    = (const float*)d_in[4];
  const float* W_hh    = (const float*)d_in[5];
  const float* b_ih    = (const float*)d_in[6];
  const float* b_hh    = (const float*)d_in[7];
  const float* att_W   = (const float*)d_in[8];
  const float* att_V   = (const float*)d_in[9];
  const float* att_b   = (const float*)d_in[10];
  const float* att_vec = (const float*)d_in[11];
  const float* W1      = (const float*)d_in[12];
  const float* b1      = (const float*)d_in[13];
  const float* W2      = (const float*)d_in[14];
  const float* b2      = (const float*)d_in[15];
  const float* W3      = (const float*)d_in[16];
  const float* b3      = (const float*)d_in[17];
  float* out = (float*)d_out;
  float* ws  = (float*)d_ws;

  rnn_prep<<<dim3(293), dim3(256), 0, stream>>>(Y, h0, outEnc, W_ih, W_hh, b_ih, b_hh,
                                                att_V, att_b, ws);
  rnn_main<<<dim3(39), dim3(512), 0, stream>>>(c0, outEnc, W_hh, att_W, att_vec,
                                               W1, b1, W2, b2, W3, b3, out, ws);
}

// Round 10
// 638.721 us; speedup vs baseline: 1.5048x; 1.5048x over previous
//
#include <hip/hip_runtime.h>
#include <stdint.h>

// ---------------------------------------------------------------------------
// DecoderRNN: 100-step LSTM + additive attention + 3-layer MLP, B=1.
// R10 = R7 (622us steady baseline) + ONE mechanism change: decongest the
// barrier flag traffic.
//   - each flag in its own 64B line (stride 16 u32): the line a publisher
//     writes is polled by only 32 lanes (1/WG), not 1024
//   - s_sleep(1) backoff in the main poll loop (cuts poll request rate ~8x)
// Everything else (phases, 4-copy craw atomics, stot atomic, bf16 att_W
// registers, clh by w0) is byte-identical to R7.
// ---------------------------------------------------------------------------

static constexpr float    L2E = 1.44269504088896341f;   // log2(e)
static constexpr float    K2  = 2.88539008177792681f;   // 2*log2(e)
static constexpr unsigned SPIN_LIMIT = 200000u;  // safety: never wedge the GPU
static constexpr int      FSTRIDE = 16;          // u32 stride: one flag per 64B line

// workspace layout (float offsets)
static constexpr size_t OFF_BC   = 0;            // [2048][256] (VOut+att_b)*K2
static constexpr size_t OFF_YG   = 524288;       // [100][1024] y@W_ih.T + b_ih + b_hh
static constexpr size_t OFF_GRAW = 626688;       // [100][1024] full gate preacts
static constexpr size_t OFF_CRAW = 729088;       // [4][100][256] ctx numerator copies
static constexpr size_t CRAW_CP  = 25600;        // copy stride
static constexpr size_t OFF_STOT = 831488;       // [100] denom accum (+pad to 128)
static constexpr size_t OFF_CLH  = 831616;       // [100][256] cLSTM history
static constexpr size_t OFF_V1   = 857216;       // [100][256]
static constexpr size_t OFF_V2   = 882816;       // [100][256]
static constexpr size_t OFF_SYNC = 908416;       // u32[1024]: flags[32*16] | fv1@512[100] | fv2@768[100]

__device__ __forceinline__ float exp2fast(float x){ return __builtin_amdgcn_exp2f(x); }
__device__ __forceinline__ float rcpfast(float x){ return __builtin_amdgcn_rcpf(x); }
__device__ __forceinline__ float sigf(float x){ return rcpfast(1.f + exp2fast(-x*L2E)); }
__device__ __forceinline__ float tanhfast(float x){
  float E = exp2fast(x*K2);            // e^{2x}; inf/0 saturate correctly
  return 1.f - 2.f*rcpfast(E + 1.f);
}
__device__ __forceinline__ unsigned short f2bf(float f){
  unsigned b = __float_as_uint(f);
  return (unsigned short)((b + 0x7FFFu + ((b>>16)&1u))>>16);
}
__device__ __forceinline__ float bf2f(unsigned short u){ return __uint_as_float(((unsigned)u)<<16); }

// sc1 (agent-scope relaxed) accesses: coherent at Infinity Cache, bypass XCD L2s
__device__ __forceinline__ void gstore(float* p, float v){
  __hip_atomic_store(p, v, __ATOMIC_RELAXED, __HIP_MEMORY_SCOPE_AGENT);
}
__device__ __forceinline__ float gload(const float* p){
  return __hip_atomic_load(p, __ATOMIC_RELAXED, __HIP_MEMORY_SCOPE_AGENT);
}
__device__ __forceinline__ void gstore_u32(unsigned* p, unsigned v){
  __hip_atomic_store(p, v, __ATOMIC_RELAXED, __HIP_MEMORY_SCOPE_AGENT);
}
__device__ __forceinline__ unsigned gload_u32(const unsigned* p){
  return __hip_atomic_load(p, __ATOMIC_RELAXED, __HIP_MEMORY_SCOPE_AGENT);
}
__device__ __forceinline__ void gatomic_addf(float* p, float v){
  (void)__hip_atomic_fetch_add(p, v, __ATOMIC_RELAXED, __HIP_MEMORY_SCOPE_AGENT);
}

// flag-array barrier: each WG writes its (line-isolated) slot; wave0 polls all
// 32 slots with s_sleep backoff.
__device__ __forceinline__ void fbar(unsigned* flags, int w, unsigned ep){
  asm volatile("s_waitcnt vmcnt(0)" ::: "memory");   // own sc1 stores/atomics at IC
  __syncthreads();
  if (threadIdx.x == 0) gstore_u32(&flags[w*FSTRIDE], ep);
  if (threadIdx.x < 64) {
    int lane = threadIdx.x;
    unsigned it = 0;
    for (;;) {
      unsigned v = (lane < 32) ? gload_u32(&flags[lane*FSTRIDE]) : ep;
      if (__all((int)(v >= ep))) break;
      __builtin_amdgcn_s_sleep(1);                   // ~64cyc backoff: decongest
      if (++it > SPIN_LIMIT) break;                  // safety
    }
  }
  __syncthreads();
}
__device__ __forceinline__ void fwait_sleep(unsigned* flags, unsigned ep){
  if (threadIdx.x < 64) {
    int lane = threadIdx.x;
    unsigned it = 0;
    for (;;) {
      unsigned v = (lane < 32) ? gload_u32(&flags[lane*FSTRIDE]) : ep;
      if (__all((int)(v >= ep))) break;
      __builtin_amdgcn_s_sleep(2);
      if (++it > SPIN_LIMIT) break;
    }
  }
  __syncthreads();
}
__device__ __forceinline__ void arrive_cnt(unsigned* cnt){
  asm volatile("s_waitcnt vmcnt(0)" ::: "memory");
  __syncthreads();
  if (threadIdx.x == 0)
    __hip_atomic_fetch_add(cnt, 1u, __ATOMIC_RELAXED, __HIP_MEMORY_SCOPE_AGENT);
}
__device__ __forceinline__ void poll_ge(unsigned* p, unsigned tgt){
  if (threadIdx.x == 0){
    unsigned it = 0;
    while (gload_u32(p) < tgt){
      __builtin_amdgcn_s_sleep(2);
      if (++it > SPIN_LIMIT) break;
    }
  }
  __syncthreads();
}

// ---------------------------------------------------------------------------
// prep kernel: Bc, yG, graw(0), sc1-zero craw/stot/sync (race-safe)
// ---------------------------------------------------------------------------
__global__ __launch_bounds__(256) void rnn_prep(
    const float* __restrict__ Y, const float* __restrict__ h0,
    const float* __restrict__ outE, const float* __restrict__ W_ih,
    const float* __restrict__ W_hh, const float* __restrict__ b_ih,
    const float* __restrict__ b_hh, const float* __restrict__ att_V,
    const float* __restrict__ att_b, float* __restrict__ ws)
{
  __shared__ float avT[32*257];
  __shared__ float oeL[8*257];
  __shared__ float yL[40];
  __shared__ float h0L[256];
  const int b = blockIdx.x, tid = threadIdx.x;
  float* ws_bc   = ws + OFF_BC;
  float* ws_yg   = ws + OFF_YG;
  float* ws_graw = ws + OFF_GRAW;

  if (b < 256) {                 // Bc[e][h] for 8 e-rows
    int e0 = b*8;
    for (int r=0;r<8;r++) oeL[r*257 + tid] = outE[(size_t)(e0+r)*256 + tid];
    int hl = tid & 31, er = tid >> 5;
    for (int ht=0; ht<8; ++ht) {
      __syncthreads();
      for (int i=0;i<32;i++){ int lin = tid + i*256; int r = lin>>8, j = lin&255;
        avT[r*257 + j] = att_V[(size_t)(ht*32+r)*256 + j]; }
      __syncthreads();
      float acc = 0.f;
      for (int j=0;j<256;j++) acc = fmaf(avT[hl*257 + j], oeL[er*257 + j], acc);
      int h = ht*32 + hl;
      ws_bc[(size_t)(e0+er)*256 + h] = (acc + att_b[h]) * K2;
    }
  } else if (b < 260) {          // yG for 25 timesteps
    int g = b - 256;
    for (int u=0; u<25; ++u) {
      int t = g*25 + u;
      __syncthreads();
      if (tid < 36) yL[tid] = Y[t*36 + tid];
      __syncthreads();
      for (int q=0;q<4;q++){
        int i = tid + 256*q;
        float acc = b_ih[i] + b_hh[i];
        for (int j=0;j<36;j++) acc = fmaf(W_ih[(size_t)i*36 + j], yL[j], acc);
        ws_yg[(size_t)t*1024 + i] = acc;
      }
    }
  } else if (b < 292) {          // graw(0) = yG(0) + W_hh@h0, 32 rows per block
    int s = b - 260;
    if (tid < 256) h0L[tid] = h0[tid];
    if (tid < 36)  yL[tid]  = Y[tid];
    __syncthreads();
    int r = tid>>3, l8 = tid&7;
    int R = s*32 + r;
    float acc = 0.f;
    for (int q=0;q<32;q++){ int j = l8*32 + q; acc = fmaf(W_hh[(size_t)R*256 + j], h0L[j], acc); }
    acc += __shfl_xor(acc,1); acc += __shfl_xor(acc,2); acc += __shfl_xor(acc,4);
    if (l8 == 0){
      float full = acc + b_ih[R] + b_hh[R];
      for (int j=0;j<36;j++) full = fmaf(W_ih[(size_t)R*36 + j], yL[j], full);
      ws_graw[R] = full;
    }
  } else if (b == 292) {         // sc1-zero sync region (1024 u32)
    unsigned* s0 = (unsigned*)(ws + OFF_SYNC);
    #pragma unroll
    for (int k=0;k<4;k++) gstore_u32(&s0[tid + k*256], 0u);
  } else if (b == 293) {         // sc1-zero stot [128]
    if (tid < 128) gstore(&ws[OFF_STOT + tid], 0.f);
  } else {                       // b in [294,394): sc1-zero craw[t], 4 copies
    int t = b - 294;
    #pragma unroll
    for (int c=0;c<4;c++)
      gstore(&ws[OFF_CRAW + (size_t)c*CRAW_CP + (size_t)t*256 + tid], 0.f);
  }
}

// ---------------------------------------------------------------------------
// persistent main kernel
// roles: w<32 main, 32..35 MLP1, 36..37 MLP2, 38 MLP3
// ---------------------------------------------------------------------------
__global__ __launch_bounds__(512, 2) void rnn_main(
    const float* __restrict__ c0, const float* __restrict__ outE,
    const float* __restrict__ W_hh, const float* __restrict__ att_W,
    const float* __restrict__ att_vec,
    const float* __restrict__ W1, const float* __restrict__ b1,
    const float* __restrict__ W2, const float* __restrict__ b2,
    const float* __restrict__ W3, const float* __restrict__ b3,
    float* __restrict__ out, float* __restrict__ ws)
{
  __shared__ __align__(16) unsigned char smem[140288];
  const int w = blockIdx.x;
  const int tid = threadIdx.x;

  float* ws_yg    = ws + OFF_YG;
  float* ws_graw  = ws + OFF_GRAW;
  float* ws_craw  = ws + OFF_CRAW;    // [4][100][256]
  float* ws_stot  = ws + OFF_STOT;    // [100]
  float* ws_clh   = ws + OFF_CLH;
  float* ws_v1    = ws + OFF_V1;
  float* ws_v2    = ws + OFF_V2;
  unsigned* flags = (unsigned*)(ws + OFF_SYNC);        // [32*16] line-isolated
  unsigned* fv1   = flags + 512;                       // [100]
  unsigned* fv2   = flags + 768;                       // [100]

  if (w < 32) {
    // ---------------- main role ----------------
    float*          bcS    = (float*)(smem);                 // [64][264] padded, *K2
    unsigned short* oeS    = (unsigned short*)(smem + 67584);// [64][256] bf16
    float*          whhS   = (float*)(smem + 100352);        // [32][260]
    float*          wsS    = (float*)(smem + 133632);        // [264] padded WS*K2
    float*          hS     = (float*)(smem + 134688);        // [256]
    float*          scoreS = (float*)(smem + 135712);        // [64]
    float*          wexpS  = (float*)(smem + 135968);        // [64]
    float*          pS     = (float*)(smem + 136224);        // [512]
    float*          avS    = (float*)(smem + 138272);        // [264] padded -2*att_vec

    // att_W rows in registers, bf16-packed: thread pair (r=tid>>1) holds 128
    // cols each as 64 u32 (2 bf16/reg).
    unsigned awP[64];
    { int r = tid>>1, p = tid&1;
      const float* arow = att_W + (size_t)r*256 + p*128;
      #pragma unroll
      for (int q=0;q<64;q++){
        unsigned lo = f2bf(arow[2*q]);
        unsigned hi = f2bf(arow[2*q+1]);
        awP[q] = lo | (hi<<16);
      } }
    float Vpart = 0.f;
    { int l8 = tid & 7;
      #pragma unroll
      for (int k=0;k<32;k++) Vpart += att_vec[l8*32 + k]; }

    const float* ws_bc = ws + OFF_BC;
    for (int i=0;i<32;i++){ int lin = tid + i*512; int col = lin>>8, h = lin&255;
      bcS[col*264 + h + (h>>5)] = ws_bc[(size_t)(w*64+col)*256 + h]; }
    for (int i=0;i<32;i++){ int lin = tid + i*512; int col = lin>>8, h = lin&255;
      oeS[col*256 + h] = f2bf(outE[(size_t)(w*64+col)*256 + h]); }
    for (int i=0;i<16;i++){ int lin = tid + i*512; int r = lin>>8, j = lin&255;
      whhS[r*260 + j] = W_hh[(size_t)(w*32+r)*256 + j]; }
    if (tid < 256) avS[tid + (tid>>5)] = -2.f * att_vec[tid];
    __syncthreads();

    for (int t = 0; t < 100; ++t) {
      // ---- phase 1: issue all cross-WG reads (sc1, pipelined) ----
      float ig, fg, gg, og;
      float cr0, cr1, cr2, cr3, st;
      if (tid < 256) {
        const float* g = ws_graw + (size_t)t*1024;
        ig = gload(&g[tid]);     fg = gload(&g[256+tid]);
        gg = gload(&g[512+tid]); og = gload(&g[768+tid]);
        if (t > 0) {
          const float* cb = ws_craw + (size_t)(t-1)*256 + tid;
          cr0 = gload(cb);             cr1 = gload(cb + CRAW_CP);
          cr2 = gload(cb + 2*CRAW_CP); cr3 = gload(cb + 3*CRAW_CP);
          st  = gload(&ws_stot[t-1]);
        }
      }
      // ---- phase 2: LSTM elementwise ----
      if (tid < 256) {
        float c;
        if (t == 0) c = c0[tid];
        else        c = ((cr0+cr1)+(cr2+cr3)) * rcpfast(st);
        float cl = sigf(fg)*c + sigf(ig)*tanhfast(gg);
        float hn = sigf(og)*tanhfast(cl);
        hS[tid] = hn;
        if (w == 0) gstore(&ws_clh[(size_t)t*256 + tid], cl);
      }
      __syncthreads();
      // ---- phase 3: WS = att_W @ h from bf16-packed registers ----
      { int r = tid>>1, p = tid&1;
        const float4* h4 = (const float4*)(hS + p*128);
        float acc = 0.f;
        #pragma unroll
        for (int i=0;i<32;i++){
          float4 hv = h4[i];
          unsigned pk0 = awP[2*i], pk1 = awP[2*i+1];
          acc = fmaf(__uint_as_float(pk0<<16),           hv.x, acc);
          acc = fmaf(__uint_as_float(pk0 & 0xffff0000u), hv.y, acc);
          acc = fmaf(__uint_as_float(pk1<<16),           hv.z, acc);
          acc = fmaf(__uint_as_float(pk1 & 0xffff0000u), hv.w, acc);
        }
        acc += __shfl_xor(acc, 1);
        if (p == 0) wsS[r + (r>>5)] = acc * K2; }
      __syncthreads();
      // ---- phase 4: scores for 64 e-cols (8 threads/col x 32 h) ----
      { int col = tid >> 3, l8 = tid & 7;
        const float* bcR = bcS + col*264 + l8*33;
        const float* wsR = wsS + l8*33;
        const float* avR = avS + l8*33;
        float acc = Vpart;
        #pragma unroll
        for (int k=0;k<32;k++){
          float E = exp2fast(bcR[k] + wsR[k]);         // e^{2x}
          acc = fmaf(avR[k], rcpfast(E + 1.f), acc);   // v*(1-2r)
        }
        acc += __shfl_xor(acc,1); acc += __shfl_xor(acc,2); acc += __shfl_xor(acc,4);
        if (l8 == 0) scoreS[col] = acc; }
      __syncthreads();
      // ---- phase 5: exp (no max; |score|<~25) + denom atomic ----
      if (tid < 64) {
        float ev = exp2fast(scoreS[tid] * L2E);
        wexpS[tid] = ev;
        float s = ev;
        #pragma unroll
        for (int d=1; d<64; d<<=1) s += __shfl_xor(s, d);
        if (tid == 0) gatomic_addf(&ws_stot[t], s);
      }
      __syncthreads();
      // ---- phase 6: partial ctx over this WG's 64 e-cols ----
      { int h = tid & 255, half = tid >> 8;
        float accp = 0.f;
        #pragma unroll
        for (int i=0;i<32;i++){ int lc = half*32 + i;
          accp = fmaf(wexpS[lc], bf2f(oeS[lc*256 + h]), accp); }
        pS[half*256 + h] = accp; }
      __syncthreads();
      if (tid < 256)
        gatomic_addf(&ws_craw[(size_t)(w>>3)*CRAW_CP + (size_t)t*256 + tid],
                     pS[tid] + pS[256 + tid]);
      // ---- phase 7: gates_raw(t+1) slice: rows w*32..w*32+31 ----
      if (t <= 98) {
        int r32 = tid >> 4, l16 = tid & 15;
        float acc2 = 0.f;
        #pragma unroll
        for (int q=0;q<16;q++){ int j = l16 + 16*q; acc2 = fmaf(whhS[r32*260 + j], hS[j], acc2); }
        acc2 += __shfl_xor(acc2,1); acc2 += __shfl_xor(acc2,2);
        acc2 += __shfl_xor(acc2,4); acc2 += __shfl_xor(acc2,8);
        if (l16 == 0){ int R = w*32 + r32;
          gstore(&ws_graw[(size_t)(t+1)*1024 + R], acc2 + ws_yg[(size_t)(t+1)*1024 + R]); }
      }
      fbar(flags, w, (unsigned)(t+1));
    }
    // epilogue: c_final = ctx(99)
    if (w == 0 && tid < 256) {
      const float* cb = ws_craw + (size_t)99*256 + tid;
      float rsum = (gload(cb) + gload(cb + CRAW_CP))
                 + (gload(cb + 2*CRAW_CP) + gload(cb + 3*CRAW_CP));
      out[3600 + tid] = rsum * rcpfast(gload(&ws_stot[99]));
    }
  } else if (w < 36) {
    // ---------------- MLP1: 64 rows of W1[256][512] ----------------
    float* wmS = (float*)(smem);
    float* vbS = (float*)(smem + 133632);
    int m = w - 32;
    for (int i=0;i<64;i++){ int lin = tid + i*512; int r = lin>>9, k = lin&511;
      wmS[r*520 + k + (k>>6)] = W1[(size_t)(m*64+r)*512 + k]; }
    __syncthreads();
    for (int s=0; s<100; ++s){
      fwait_sleep(flags, (unsigned)(s+1));
      { float val;
        if (tid < 256) val = gload(&ws_clh[(size_t)s*256 + tid]);
        else {
          const float* cb = ws_craw + (size_t)s*256 + (tid-256);
          float rsum = (gload(cb) + gload(cb + CRAW_CP))
                     + (gload(cb + 2*CRAW_CP) + gload(cb + 3*CRAW_CP));
          val = rsum * rcpfast(gload(&ws_stot[s]));
        }
        vbS[tid + (tid>>6)] = val; }
      __syncthreads();
      int row = tid >> 3, l8 = tid & 7;
      const float* wr = wmS + row*520 + l8*65;
      const float* vr = vbS + l8*65;
      float acc = 0.f;
      #pragma unroll
      for (int q=0;q<64;q++) acc = fmaf(wr[q], vr[q], acc);
      acc += __shfl_xor(acc,1); acc += __shfl_xor(acc,2); acc += __shfl_xor(acc,4);
      if (l8 == 0){ int i = m*64 + row; gstore(&ws_v1[(size_t)s*256 + i], fmaxf(acc + b1[i], 0.f)); }
      arrive_cnt(&fv1[s]);
      __syncthreads();
    }
  } else if (w < 38) {
    // ---------------- MLP2: 128 rows of W2[256][256] ----------------
    float* wmS = (float*)(smem);
    float* vbS = (float*)(smem + 133632);
    int m = w - 36;
    for (int i=0;i<64;i++){ int lin = tid + i*512; int r = lin>>8, k = lin&255;
      wmS[r*260 + k + (k>>6)] = W2[(size_t)(m*128+r)*256 + k]; }
    __syncthreads();
    for (int s=0; s<100; ++s){
      poll_ge(&fv1[s], 4u);
      if (tid < 256) vbS[tid + (tid>>6)] = gload(&ws_v1[(size_t)s*256 + tid]);
      __syncthreads();
      int row = tid >> 2, l4 = tid & 3;
      const float* wr = wmS + row*260 + l4*65;
      const float* vr = vbS + l4*65;
      float acc = 0.f;
      #pragma unroll
      for (int q=0;q<64;q++) acc = fmaf(wr[q], vr[q], acc);
      acc += __shfl_xor(acc,1); acc += __shfl_xor(acc,2);
      if (l4 == 0){ int i = m*128 + row; gstore(&ws_v2[(size_t)s*256 + i], fmaxf(acc + b2[i], 0.f)); }
      arrive_cnt(&fv2[s]);
      __syncthreads();
    }
  } else {
    // ---------------- MLP3: W3[36][256] -> out ----------------
    float* wmS = (float*)(smem);
    float* vbS = (float*)(smem + 37440);
    for (int lin = tid; lin < 36*256; lin += 512){ int r = lin>>8, k = lin&255;
      wmS[r*260 + k + (k>>6)] = W3[(size_t)r*256 + k]; }
    __syncthreads();
    for (int s=0; s<100; ++s){
      poll_ge(&fv2[s], 2u);
      if (tid < 256) vbS[tid + (tid>>6)] = gload(&ws_v2[(size_t)s*256 + tid]);
      __syncthreads();
      if (tid < 288) {
        int row = tid >> 3, l8 = tid & 7;
        int kb = l8*32;
        const float* wr = wmS + row*260 + kb + (kb>>6);
        const float* vr = vbS + kb + (kb>>6);
        float acc = 0.f;
        #pragma unroll
        for (int q=0;q<32;q++) acc = fmaf(wr[q], vr[q], acc);
        acc += __shfl_xor(acc,1); acc += __shfl_xor(acc,2); acc += __shfl_xor(acc,4);
        if (l8 == 0) out[s*36 + row] = acc + b3[row];   // visible at kernel end
      }
      __syncthreads();
    }
  }
}

// ---------------------------------------------------------------------------
extern "C" void kernel_launch(void* const* d_in, const int* in_sizes, int n_in,
                              void* d_out, int out_size, void* d_ws, size_t ws_size,
                              hipStream_t stream) {
  (void)in_sizes; (void)n_in; (void)out_size; (void)ws_size;
  const float* Y       = (const float*)d_in[0];
  const float* h0      = (const float*)d_in[1];
  const float* c0      = (const float*)d_in[2];
  const float* outEnc  = (const float*)d_in[3];
  const float* W_ih    = (const float*)d_in[4];
  const float* W_hh    = (const float*)d_in[5];
  const float* b_ih    = (const float*)d_in[6];
  const float* b_hh    = (const float*)d_in[7];
  const float* att_W   = (const float*)d_in[8];
  const float* att_V   = (const float*)d_in[9];
  const float* att_b   = (const float*)d_in[10];
  const float* att_vec = (const float*)d_in[11];
  const float* W1      = (const float*)d_in[12];
  const float* b1      = (const float*)d_in[13];
  const float* W2      = (const float*)d_in[14];
  const float* b2      = (const float*)d_in[15];
  const float* W3      = (const float*)d_in[16];
  const float* b3      = (const float*)d_in[17];
  float* out = (float*)d_out;
  float* ws  = (float*)d_ws;

  rnn_prep<<<dim3(394), dim3(256), 0, stream>>>(Y, h0, outEnc, W_ih, W_hh, b_ih, b_hh,
                                                att_V, att_b, ws);
  rnn_main<<<dim3(39), dim3(512), 0, stream>>>(c0, outEnc, W_hh, att_W, att_vec,
                                               W1, b1, W2, b2, W3, b3, out, ws);
}